// Round 3
// baseline (898.544 us; speedup 1.0000x reference)
//
#include <hip/hip_runtime.h>
#include <math.h>

#define C_DIM 256
#define HW_DIM 1024
#define N_DIM 64
#define M_TOTAL (N_DIM * HW_DIM)   // 65536
#define EPS_F 1e-5f
#define NSB 128                     // blocks in persistent NS kernel

typedef __attribute__((ext_vector_type(8))) short short8;   // 8 bf16 (MFMA A/B frag)
typedef __attribute__((ext_vector_type(4))) float v4f;      // MFMA C/D frag

// fp32 -> bf16 round-to-nearest-even
__device__ __forceinline__ unsigned short f2bf(float x) {
    unsigned u = __float_as_uint(x);
    u = (u + 0x7FFFu + ((u >> 16) & 1u)) >> 16;
    return (unsigned short)u;
}
__device__ __forceinline__ unsigned pack2(float lo, float hi) {
    return (unsigned)f2bf(lo) | ((unsigned)f2bf(hi) << 16);
}

// ---------------------------------------------------------------------------
// Kernel 1: Xbf = bf16(X) + per-channel sums (atomic). grid 4096, block 256.
// Block handles 4 consecutive (n,c) rows; thread t -> row t>>6, wave-aligned.
__global__ void prepass_kernel(const float* __restrict__ X, unsigned short* __restrict__ Xbf,
                               float* __restrict__ musum) {
    int b = blockIdx.x;            // 4 rows per block: rows 4b..4b+3 of 16384
    int t = threadIdx.x;
    int r = t >> 6;                // 0..3 (one wave per row)
    int l = t & 63;
    size_t row = (size_t)(4 * b + r);
    const float4* src = (const float4*)(X + (row << 10));
    uint2* dst = (uint2*)(Xbf + (row << 10));
    float s = 0.f;
#pragma unroll
    for (int j = 0; j < 4; ++j) {
        float4 v = src[l + 64 * j];
        uint2 p; p.x = pack2(v.x, v.y); p.y = pack2(v.z, v.w);
        dst[l + 64 * j] = p;
        s += v.x + v.y + v.z + v.w;
    }
    for (int off = 32; off > 0; off >>= 1) s += __shfl_down(s, off);
    if (l == 0) atomicAdd(&musum[(4 * b + r) & 255], s);
}

// ---------------------------------------------------------------------------
// Kernel 2: raw Gram G += X X^T via bf16 MFMA, symmetric (3 unique tiles).
// grid (3 tiles, 128 k-splits), block 512 (8 waves: 2x4 of 64x32).
__global__ __launch_bounds__(512, 3)
void gram_mfma(const unsigned short* __restrict__ Xbf, float* __restrict__ G) {
    int tile = blockIdx.x;               // 0:(0,0) 1:(0,128) 2:(128,128)
    int ci = (tile >> 1) * 128;
    int cj = (tile == 0) ? 0 : 128;
    int ks = blockIdx.y;                 // 0..127, K=512 each
    int t = threadIdx.x, wave = t >> 6, lane = t & 63;
    int wy = wave >> 2, wx = wave & 3;   // 2 x 4
    int quad = lane >> 4, l16 = lane & 15;

    __shared__ __align__(16) unsigned short As[128 * 72];  // stride 144B (2-way = free)
    __shared__ __align__(16) unsigned short Bs[128 * 72];
    const unsigned short* Bsrc = (ci == cj) ? As : Bs;

    v4f acc[4][2] = {};
    int n = ks >> 1;
    int hwbase = (ks & 1) * 512;
    const unsigned short* base = Xbf + (((size_t)n * C_DIM) << 10);
    int srow = t >> 2;                   // 0..127
    int schunk = t & 3;                  // uint4 chunk, +{0,4}

    for (int s = 0; s < 8; ++s) {        // 8 stages of BK=64
        int k0 = hwbase + s * 64;
        __syncthreads();
#pragma unroll
        for (int h = 0; h < 2; ++h) {
            int ch = schunk + 4 * h;
            *(uint4*)&As[srow * 72 + ch * 8] =
                *(const uint4*)&base[(((size_t)(ci + srow)) << 10) + k0 + ch * 8];
            if (ci != cj)
                *(uint4*)&Bs[srow * 72 + ch * 8] =
                    *(const uint4*)&base[(((size_t)(cj + srow)) << 10) + k0 + ch * 8];
        }
        __syncthreads();

        short8 af[4][2], bfr[2][2];
#pragma unroll
        for (int mt = 0; mt < 4; ++mt)
#pragma unroll
            for (int kh = 0; kh < 2; ++kh)
                af[mt][kh] = *(const short8*)&As[(64 * wy + 16 * mt + l16) * 72 + kh * 32 + quad * 8];
#pragma unroll
        for (int nt = 0; nt < 2; ++nt)
#pragma unroll
            for (int kh = 0; kh < 2; ++kh)
                bfr[nt][kh] = *(const short8*)&Bsrc[(32 * wx + 16 * nt + l16) * 72 + kh * 32 + quad * 8];
#pragma unroll
        for (int kh = 0; kh < 2; ++kh)
#pragma unroll
            for (int mt = 0; mt < 4; ++mt)
#pragma unroll
                for (int nt = 0; nt < 2; ++nt)
                    acc[mt][nt] = __builtin_amdgcn_mfma_f32_16x16x32_bf16(af[mt][kh], bfr[nt][kh], acc[mt][nt], 0, 0, 0);
    }

#pragma unroll
    for (int mt = 0; mt < 4; ++mt)
#pragma unroll
        for (int nt = 0; nt < 2; ++nt)
#pragma unroll
            for (int r = 0; r < 4; ++r) {
                int row = ci + 64 * wy + 16 * mt + 4 * quad + r;
                int col = cj + 32 * wx + 16 * nt + l16;
                atomicAdd(&G[row * C_DIM + col], acc[mt][nt][r]);
            }
}

// ---------------------------------------------------------------------------
// Kernel 3: scal[0] = 1/trace(Sigma), scal[1] = sqrt(scal[0]). grid 1, block 256.
__global__ void scal_kernel(const float* __restrict__ G, const float* __restrict__ musum,
                            float* __restrict__ scal) {
    int t = threadIdx.x;
    float mu = musum[t] * (1.0f / M_TOTAL);
    float d = G[t * (C_DIM + 1)] * (1.0f / M_TOTAL) - mu * mu + EPS_F;
    __shared__ float red[256];
    red[t] = d;
    __syncthreads();
    for (int off = 128; off > 0; off >>= 1) {
        if (t < off) red[t] += red[t + off];
        __syncthreads();
    }
    if (t == 0) {
        float tr_rec = 1.0f / red[0];
        scal[0] = tr_rec;
        scal[1] = sqrtf(tr_rec);
    }
}

// ---------------------------------------------------------------------------
// 256x256 fp32 matmul tile body. MODE 0: D=A@B ; 1: D=1.5D-0.5(A@B) ; 2: D=(A@B)*scal[1]
template <int MODE>
__device__ void mm256_body(const float* __restrict__ A, const float* __restrict__ B,
                           float* __restrict__ D, const float* __restrict__ scal, int tile) {
    int ci = (tile >> 3) * 32, cj = (tile & 7) * 32;
    int t = threadIdx.x;
    int ty = t >> 4, tx = t & 15;
    __shared__ float As[32][33], Bs[32][33];
    float acc[2][2] = {};

    for (int kb = 0; kb < 256; kb += 32) {
        {
            int kk = t & 31, r0 = t >> 5;
#pragma unroll
            for (int i = 0; i < 4; ++i)
                As[r0 + 8 * i][kk] = A[(ci + r0 + 8 * i) * C_DIM + kb + kk];
            int cP = t & 31, k2 = t >> 5;
#pragma unroll
            for (int i = 0; i < 4; ++i)
                Bs[cP][k2 + 8 * i] = B[(kb + k2 + 8 * i) * C_DIM + cj + cP];
        }
        __syncthreads();
#pragma unroll
        for (int k = 0; k < 32; ++k) {
            float a0 = As[ty][k], a1 = As[ty + 16][k];
            float b0 = Bs[tx][k], b1 = Bs[tx + 16][k];
            acc[0][0] += a0 * b0; acc[0][1] += a0 * b1;
            acc[1][0] += a1 * b0; acc[1][1] += a1 * b1;
        }
        __syncthreads();
    }
#pragma unroll
    for (int u = 0; u < 2; ++u)
#pragma unroll
        for (int v = 0; v < 2; ++v) {
            int r = ci + ty + 16 * u, cc = cj + tx + 16 * v;
            float val = acc[u][v];
            if (MODE == 0)      D[r * C_DIM + cc] = val;
            else if (MODE == 1) D[r * C_DIM + cc] = 1.5f * D[r * C_DIM + cc] - 0.5f * val;
            else                D[r * C_DIM + cc] = val * scal[1];
        }
}

// Grid barrier: monotone counter, device-scope atomics + agent fences.
// Safe: 128 blocks <= 256 CUs => all co-resident; uniform barrier count per block.
__device__ __forceinline__ void grid_bar(unsigned* cnt, unsigned target) {
    __syncthreads();
    if (threadIdx.x == 0) {
        __threadfence();
        __hip_atomic_fetch_add(cnt, 1u, __ATOMIC_ACQ_REL, __HIP_MEMORY_SCOPE_AGENT);
        while (__hip_atomic_load(cnt, __ATOMIC_ACQUIRE, __HIP_MEMORY_SCOPE_AGENT) < target)
            __builtin_amdgcn_s_sleep(2);
        __threadfence();
    }
    __syncthreads();
}

// ---------------------------------------------------------------------------
// Kernel 4: persistent Newton-Schulz + rot + mprep. grid NSB=128, block 256.
// Phases: init (Sig=Sigma_N, P1=1.5I-0.5*Sig) | 9x(T1=P@P & T2=P@Sig ; P=1.5P-0.5*T1@T2)
//         | Mm=(R@P)*scal[1] | Mbf=bf16(Mm), moff=Mm@mu
__global__ void ns_kernel(const float* __restrict__ G, const float* __restrict__ musum,
                          const float* __restrict__ scal, float* __restrict__ Sig,
                          float* __restrict__ P, float* __restrict__ T1, float* __restrict__ T2,
                          const float* __restrict__ R, float* __restrict__ Mm,
                          unsigned short* __restrict__ Mbf, float* __restrict__ moff,
                          unsigned* __restrict__ cnt) {
    int b = blockIdx.x, t = threadIdx.x;
    unsigned phase = 0;

    // init: Sigma_N from raw Gram (+ symmetric mirror), P = 1.5I - 0.5*Sigma_N
    float trr = scal[0];
#pragma unroll
    for (int j = 0; j < 2; ++j) {
        int idx = b * 512 + j * 256 + t;
        int r = idx >> 8, c = idx & 255;
        float g = (r >= 128 && c < 128) ? G[c * C_DIM + r] : G[idx];
        float mu_r = musum[r] * (1.0f / M_TOTAL);
        float mu_c = musum[c] * (1.0f / M_TOTAL);
        float sig = (g * (1.0f / M_TOTAL) - mu_r * mu_c + ((r == c) ? EPS_F : 0.f)) * trr;
        Sig[idx] = sig;
        P[idx] = ((r == c) ? 1.5f : 0.f) - 0.5f * sig;
    }
    grid_bar(cnt, ++phase * NSB);

    for (int it = 1; it < 10; ++it) {
        if (b < 64) mm256_body<0>(P, P,   T1, nullptr, b);
        else        mm256_body<0>(P, Sig, T2, nullptr, b - 64);
        grid_bar(cnt, ++phase * NSB);
        if (b < 64) mm256_body<1>(T1, T2, P, nullptr, b);
        grid_bar(cnt, ++phase * NSB);
    }

    if (b < 64) mm256_body<2>(R, P, Mm, scal, b);
    grid_bar(cnt, ++phase * NSB);

    // Mbf pack (512 elems/block) + moff rows 2b, 2b+1
#pragma unroll
    for (int j = 0; j < 2; ++j) {
        int idx = b * 512 + j * 256 + t;
        Mbf[idx] = f2bf(Mm[idx]);
    }
    __shared__ float red[256];
#pragma unroll
    for (int rr = 0; rr < 2; ++rr) {
        int d = 2 * b + rr;
        red[t] = Mm[d * C_DIM + t] * musum[t] * (1.0f / M_TOTAL);
        __syncthreads();
        for (int off = 128; off > 0; off >>= 1) {
            if (t < off) red[t] += red[t + off];
            __syncthreads();
        }
        if (t == 0) moff[d] = red[0];
        __syncthreads();
    }
}

// ---------------------------------------------------------------------------
// Kernel 5: out[n,d,hw] = sum_c Mbf[d,c]*Xbf[n,c,hw] - moff[d]  via MFMA
// grid: (8 hw-tiles, 2 d-tiles, 64 n), block 256 (4 waves of 64x64)
__global__ void out_mfma(const unsigned short* __restrict__ Xbf,
                         const unsigned short* __restrict__ Mbf,
                         const float* __restrict__ moff, float* __restrict__ out) {
    int hwb = blockIdx.x * 128;
    int db  = blockIdx.y * 128;
    int n   = blockIdx.z;
    int t = threadIdx.x, wave = t >> 6, lane = t & 63;
    int wy = wave >> 1, wx = wave & 1, quad = lane >> 4, l16 = lane & 15;

    __shared__ __align__(16) unsigned short Asm[128 * 40];  // M tile [d][c]
    __shared__ __align__(16) unsigned short Bsm[128 * 34];  // X^T tile [hw][c]

    v4f acc[4][4] = {};
    const unsigned short* Xn = Xbf + (((size_t)n * C_DIM) << 10);

    for (int kb = 0; kb < 256; kb += 32) {
        __syncthreads();
#pragma unroll
        for (int i = 0; i < 2; ++i) {
            int a = t + 256 * i;                 // 512 x uint4
            int row = a >> 2, c8 = a & 3;
            *(uint4*)(&Asm[row * 40 + 8 * c8]) =
                *(const uint4*)(&Mbf[(db + row) * C_DIM + kb + 8 * c8]);
        }
        // B transposed: hw across lanes -> coalesced 2B loads, conflict-free LDS stores
#pragma unroll
        for (int i = 0; i < 16; ++i) {
            int idx = t + 256 * i;               // 0..4095 ushorts
            int hw = idx & 127, crow = idx >> 7; // crow 0..31
            Bsm[hw * 34 + crow] = Xn[(((size_t)(kb + crow)) << 10) + hwb + hw];
        }
        __syncthreads();

        short8 af[4], bfr[4];
#pragma unroll
        for (int mt = 0; mt < 4; ++mt)
            af[mt] = *(const short8*)(&Asm[(64 * wy + 16 * mt + l16) * 40 + 8 * quad]);
#pragma unroll
        for (int nt = 0; nt < 4; ++nt) {
            union { short8 s; unsigned u[4]; } tmp;
            const unsigned short* bp = &Bsm[(64 * wx + 16 * nt + l16) * 34 + 8 * quad];
            tmp.u[0] = *(const unsigned*)(bp + 0);
            tmp.u[1] = *(const unsigned*)(bp + 2);
            tmp.u[2] = *(const unsigned*)(bp + 4);
            tmp.u[3] = *(const unsigned*)(bp + 6);
            bfr[nt] = tmp.s;
        }
#pragma unroll
        for (int mt = 0; mt < 4; ++mt)
#pragma unroll
            for (int nt = 0; nt < 4; ++nt)
                acc[mt][nt] = __builtin_amdgcn_mfma_f32_16x16x32_bf16(af[mt], bfr[nt], acc[mt][nt], 0, 0, 0);
    }

#pragma unroll
    for (int mt = 0; mt < 4; ++mt)
#pragma unroll
        for (int r = 0; r < 4; ++r) {
            int d = db + 64 * wy + 16 * mt + quad * 4 + r;
            float off = moff[d];
#pragma unroll
            for (int nt = 0; nt < 4; ++nt) {
                int hw = hwb + 64 * wx + 16 * nt + l16;
                out[(((size_t)(n * C_DIM + d)) << 10) + hw] = acc[mt][nt][r] - off;
            }
        }
}

// ---------------------------------------------------------------------------
extern "C" void kernel_launch(void* const* d_in, const int* in_sizes, int n_in,
                              void* d_out, int out_size, void* d_ws, size_t ws_size,
                              hipStream_t stream) {
    const float* X = (const float*)d_in[0];        // (64,256,32,32)
    const float* R = (const float*)d_in[1];        // (1,256,256)
    float* out = (float*)d_out;
    float* ws  = (float*)d_ws;

    float* musum = ws;                         // 256
    float* scal  = ws + 256;                   // 16
    unsigned* cnt = (unsigned*)(ws + 272);     // 16
    float* G   = ws + 288;                     // 65536 (raw gram, upper tiles)
    float* Sig = G + 65536;                    // Sigma_N
    float* P   = Sig + 65536;
    float* T1  = P + 65536;
    float* T2  = T1 + 65536;
    float* Mm  = T2 + 65536;
    float* moff = Mm + 65536;                  // 256
    unsigned short* Mbf = (unsigned short*)(moff + 256);          // 65536 ushort
    unsigned short* Xbf = (unsigned short*)(moff + 256 + 32768);  // 16M ushort (32 MB)

    // zero musum/scal/cnt/G in one memset (head region)
    hipMemsetAsync(ws, 0, (288 + 65536) * sizeof(float), stream);

    prepass_kernel<<<4096, 256, 0, stream>>>(X, Xbf, musum);
    gram_mfma<<<dim3(3, 128), 512, 0, stream>>>(Xbf, G);
    scal_kernel<<<1, 256, 0, stream>>>(G, musum, scal);
    ns_kernel<<<NSB, 256, 0, stream>>>(G, musum, scal, Sig, P, T1, T2, R, Mm, Mbf, moff, cnt);
    out_mfma<<<dim3(8, 2, 64), 256, 0, stream>>>(Xbf, Mbf, moff, out);
}

// Round 4
// 711.468 us; speedup vs baseline: 1.2629x; 1.2629x over previous
//
#include <hip/hip_runtime.h>
#include <math.h>

#define C_DIM 256
#define HW_DIM 1024
#define N_DIM 64
#define M_TOTAL (N_DIM * HW_DIM)   // 65536
#define EPS_F 1e-5f

typedef __attribute__((ext_vector_type(8))) short short8;   // 8 bf16 (MFMA A/B frag)
typedef __attribute__((ext_vector_type(4))) float v4f;      // MFMA C/D frag

// fp32 -> bf16 round-to-nearest-even
__device__ __forceinline__ unsigned short f2bf(float x) {
    unsigned u = __float_as_uint(x);
    u = (u + 0x7FFFu + ((u >> 16) & 1u)) >> 16;
    return (unsigned short)u;
}
__device__ __forceinline__ unsigned pack2(float lo, float hi) {
    return (unsigned)f2bf(lo) | ((unsigned)f2bf(hi) << 16);
}

// ---------------------------------------------------------------------------
// Kernel 1: Xbf = bf16(X) + per-channel sums (atomic). grid 4096, block 256.
__global__ void prepass_kernel(const float* __restrict__ X, unsigned short* __restrict__ Xbf,
                               float* __restrict__ musum) {
    int b = blockIdx.x;
    int t = threadIdx.x;
    int r = t >> 6;                // 0..3 (one wave per row)
    int l = t & 63;
    size_t row = (size_t)(4 * b + r);
    const float4* src = (const float4*)(X + (row << 10));
    uint2* dst = (uint2*)(Xbf + (row << 10));
    float s = 0.f;
#pragma unroll
    for (int j = 0; j < 4; ++j) {
        float4 v = src[l + 64 * j];
        uint2 p; p.x = pack2(v.x, v.y); p.y = pack2(v.z, v.w);
        dst[l + 64 * j] = p;
        s += v.x + v.y + v.z + v.w;
    }
    for (int off = 32; off > 0; off >>= 1) s += __shfl_down(s, off);
    if (l == 0) atomicAdd(&musum[(4 * b + r) & 255], s);
}

// ---------------------------------------------------------------------------
// Kernel 2: raw Gram G += X X^T via bf16 MFMA, symmetric (3 unique tiles).
// grid (3 tiles, 128 k-splits), block 512 (8 waves: 2x4 of 64x32).
__global__ __launch_bounds__(512, 3)
void gram_mfma(const unsigned short* __restrict__ Xbf, float* __restrict__ G) {
    int tile = blockIdx.x;               // 0:(0,0) 1:(0,128) 2:(128,128)
    int ci = (tile >> 1) * 128;
    int cj = (tile == 0) ? 0 : 128;
    int ks = blockIdx.y;                 // 0..127, K=512 each
    int t = threadIdx.x, wave = t >> 6, lane = t & 63;
    int wy = wave >> 2, wx = wave & 3;   // 2 x 4
    int quad = lane >> 4, l16 = lane & 15;

    __shared__ __align__(16) unsigned short As[128 * 72];
    __shared__ __align__(16) unsigned short Bs[128 * 72];
    const unsigned short* Bsrc = (ci == cj) ? As : Bs;

    v4f acc[4][2] = {};
    int n = ks >> 1;
    int hwbase = (ks & 1) * 512;
    const unsigned short* base = Xbf + (((size_t)n * C_DIM) << 10);
    int srow = t >> 2;
    int schunk = t & 3;

    for (int s = 0; s < 8; ++s) {
        int k0 = hwbase + s * 64;
        __syncthreads();
#pragma unroll
        for (int h = 0; h < 2; ++h) {
            int ch = schunk + 4 * h;
            *(uint4*)&As[srow * 72 + ch * 8] =
                *(const uint4*)&base[(((size_t)(ci + srow)) << 10) + k0 + ch * 8];
            if (ci != cj)
                *(uint4*)&Bs[srow * 72 + ch * 8] =
                    *(const uint4*)&base[(((size_t)(cj + srow)) << 10) + k0 + ch * 8];
        }
        __syncthreads();

        short8 af[4][2], bfr[2][2];
#pragma unroll
        for (int mt = 0; mt < 4; ++mt)
#pragma unroll
            for (int kh = 0; kh < 2; ++kh)
                af[mt][kh] = *(const short8*)&As[(64 * wy + 16 * mt + l16) * 72 + kh * 32 + quad * 8];
#pragma unroll
        for (int nt = 0; nt < 2; ++nt)
#pragma unroll
            for (int kh = 0; kh < 2; ++kh)
                bfr[nt][kh] = *(const short8*)&Bsrc[(32 * wx + 16 * nt + l16) * 72 + kh * 32 + quad * 8];
#pragma unroll
        for (int kh = 0; kh < 2; ++kh)
#pragma unroll
            for (int mt = 0; mt < 4; ++mt)
#pragma unroll
                for (int nt = 0; nt < 2; ++nt)
                    acc[mt][nt] = __builtin_amdgcn_mfma_f32_16x16x32_bf16(af[mt][kh], bfr[nt][kh], acc[mt][nt], 0, 0, 0);
    }

#pragma unroll
    for (int mt = 0; mt < 4; ++mt)
#pragma unroll
        for (int nt = 0; nt < 2; ++nt)
#pragma unroll
            for (int r = 0; r < 4; ++r) {
                int row = ci + 64 * wy + 16 * mt + 4 * quad + r;
                int col = cj + 32 * wx + 16 * nt + l16;
                atomicAdd(&G[row * C_DIM + col], acc[mt][nt][r]);
            }
}

// ---------------------------------------------------------------------------
// Kernel 3: scal[0]=1/trace(Sigma), scal[1]=sqrt(scal[0]). grid 1, block 256.
__global__ void scal_kernel(const float* __restrict__ G, const float* __restrict__ musum,
                            float* __restrict__ scal) {
    int t = threadIdx.x;
    float mu = musum[t] * (1.0f / M_TOTAL);
    float d = G[t * (C_DIM + 1)] * (1.0f / M_TOTAL) - mu * mu + EPS_F;
    __shared__ float red[256];
    red[t] = d;
    __syncthreads();
    for (int off = 128; off > 0; off >>= 1) {
        if (t < off) red[t] += red[t + off];
        __syncthreads();
    }
    if (t == 0) {
        float tr_rec = 1.0f / red[0];
        scal[0] = tr_rec;
        scal[1] = sqrtf(tr_rec);
    }
}

// ---------------------------------------------------------------------------
// Kernel 4: Sig = Sigma_N (fp32, mirrored), P = 1.5I - 0.5*Sig. grid 64, block 256.
__global__ void init_kernel(const float* __restrict__ G, const float* __restrict__ musum,
                            const float* __restrict__ scal, float* __restrict__ Sig,
                            float* __restrict__ P) {
    float trr = scal[0];
    int base = blockIdx.x * 1024 + threadIdx.x;
#pragma unroll
    for (int j = 0; j < 4; ++j) {
        int idx = base + j * 256;
        int r = idx >> 8, c = idx & 255;
        float g = (r >= 128 && c < 128) ? G[c * C_DIM + r] : G[idx];
        float mu_r = musum[r] * (1.0f / M_TOTAL);
        float mu_c = musum[c] * (1.0f / M_TOTAL);
        float sig = (g * (1.0f / M_TOTAL) - mu_r * mu_c + ((r == c) ? EPS_F : 0.f)) * trr;
        Sig[idx] = sig;
        P[idx] = ((r == c) ? 1.5f : 0.f) - 0.5f * sig;
    }
}

// ---------------------------------------------------------------------------
// 64x64-tile fp32 matmul body (K=256). tile in 0..15. block 256, 4x4 micro.
// MODE 0: D = A@B ; MODE 1: D = 1.5*D - 0.5*(A@B)
template <int MODE>
__device__ void mm64_body(const float* __restrict__ A, const float* __restrict__ B,
                          float* __restrict__ D, int tile) {
    int ci = (tile >> 2) * 64, cj = (tile & 3) * 64;
    int t = threadIdx.x;
    int ty = t >> 4, tx = t & 15;
    __shared__ float As[64][33], Bs[64][33];   // As[row][k], Bs[col][k]
    float acc[4][4] = {};

    for (int kb = 0; kb < 256; kb += 32) {
        {
            int k = t & 31, r0 = t >> 5;       // A: 64x32 scalar, 8/thread
#pragma unroll
            for (int i = 0; i < 8; ++i)
                As[r0 + 8 * i][k] = A[(ci + r0 + 8 * i) * C_DIM + kb + k];
            int c = t & 63, kr = t >> 6;       // B: coalesced read, transposed store
#pragma unroll
            for (int i = 0; i < 8; ++i)
                Bs[c][kr + 4 * i] = B[(kb + kr + 4 * i) * C_DIM + cj + c];
        }
        __syncthreads();
#pragma unroll
        for (int k = 0; k < 32; ++k) {
            float a[4], b[4];
#pragma unroll
            for (int u = 0; u < 4; ++u) { a[u] = As[ty + 16 * u][k]; b[u] = Bs[tx + 16 * u][k]; }
#pragma unroll
            for (int u = 0; u < 4; ++u)
#pragma unroll
                for (int v = 0; v < 4; ++v) acc[u][v] += a[u] * b[v];
        }
        __syncthreads();
    }
#pragma unroll
    for (int u = 0; u < 4; ++u)
#pragma unroll
        for (int v = 0; v < 4; ++v) {
            int r = ci + ty + 16 * u, cc = cj + tx + 16 * v;
            if (MODE == 0) D[r * C_DIM + cc] = acc[u][v];
            else           D[r * C_DIM + cc] = 1.5f * D[r * C_DIM + cc] - 0.5f * acc[u][v];
        }
}

// NS level 1: T1 = P@P (y=0), T2 = P@Sigma_N (y=1). grid (16,2), block 256.
__global__ void nsA_kernel(const float* __restrict__ P, const float* __restrict__ Sig,
                           float* __restrict__ T1, float* __restrict__ T2) {
    if (blockIdx.y == 0) mm64_body<0>(P, P,   T1, blockIdx.x);
    else                 mm64_body<0>(P, Sig, T2, blockIdx.x);
}
// NS level 2: P = 1.5P - 0.5*(T1@T2). grid 16, block 256.
__global__ void nsB_kernel(const float* __restrict__ T1, const float* __restrict__ T2,
                           float* __restrict__ P) {
    mm64_body<1>(T1, T2, P, blockIdx.x);
}

// ---------------------------------------------------------------------------
// Kernel 5: rot + pack + moff fused. Mbf = bf16((R@P)*scal[1]);
// moff[r] += sum_c val[r][c]*mu[c] (block-reduced, 4 atomics/row). grid 16, block 256.
__global__ void rot_kernel(const float* __restrict__ R, const float* __restrict__ P,
                           const float* __restrict__ scal, const float* __restrict__ musum,
                           unsigned short* __restrict__ Mbf, float* __restrict__ moff) {
    int tile = blockIdx.x;
    int ci = (tile >> 2) * 64, cj = (tile & 3) * 64;
    int t = threadIdx.x;
    int ty = t >> 4, tx = t & 15;
    __shared__ float As[64][33], Bs[64][33];
    __shared__ float Pred[64][17];
    float acc[4][4] = {};

    for (int kb = 0; kb < 256; kb += 32) {
        {
            int k = t & 31, r0 = t >> 5;
#pragma unroll
            for (int i = 0; i < 8; ++i)
                As[r0 + 8 * i][k] = R[(ci + r0 + 8 * i) * C_DIM + kb + k];
            int c = t & 63, kr = t >> 6;
#pragma unroll
            for (int i = 0; i < 8; ++i)
                Bs[c][kr + 4 * i] = P[(kb + kr + 4 * i) * C_DIM + cj + c];
        }
        __syncthreads();
#pragma unroll
        for (int k = 0; k < 32; ++k) {
            float a[4], b[4];
#pragma unroll
            for (int u = 0; u < 4; ++u) { a[u] = As[ty + 16 * u][k]; b[u] = Bs[tx + 16 * u][k]; }
#pragma unroll
            for (int u = 0; u < 4; ++u)
#pragma unroll
                for (int v = 0; v < 4; ++v) acc[u][v] += a[u] * b[v];
        }
        __syncthreads();
    }

    float s1 = scal[1];
    float muc[4];
#pragma unroll
    for (int v = 0; v < 4; ++v) muc[v] = musum[cj + tx + 16 * v] * (1.0f / M_TOTAL);
#pragma unroll
    for (int u = 0; u < 4; ++u) {
        float p = 0.f;
#pragma unroll
        for (int v = 0; v < 4; ++v) {
            float val = acc[u][v] * s1;
            Mbf[(ci + ty + 16 * u) * C_DIM + cj + tx + 16 * v] = f2bf(val);
            p += val * muc[v];
        }
        Pred[ty + 16 * u][tx] = p;
    }
    __syncthreads();
    if (t < 64) {
        float s = 0.f;
#pragma unroll
        for (int x = 0; x < 16; ++x) s += Pred[t][x];
        atomicAdd(&moff[ci + t], s);
    }
}

// ---------------------------------------------------------------------------
// Kernel 6: out[n,d,hw] = sum_c Mbf[d,c]*Xbf[n,c,hw] - moff[d]  via MFMA
// grid: (8 hw-tiles, 2 d-tiles, 64 n), block 256 (4 waves of 64x64)
__global__ void out_mfma(const unsigned short* __restrict__ Xbf,
                         const unsigned short* __restrict__ Mbf,
                         const float* __restrict__ moff, float* __restrict__ out) {
    int hwb = blockIdx.x * 128;
    int db  = blockIdx.y * 128;
    int n   = blockIdx.z;
    int t = threadIdx.x, wave = t >> 6, lane = t & 63;
    int wy = wave >> 1, wx = wave & 1, quad = lane >> 4, l16 = lane & 15;

    __shared__ __align__(16) unsigned short Asm[128 * 40];
    __shared__ __align__(16) unsigned short Bsm[128 * 34];

    v4f acc[4][4] = {};
    const unsigned short* Xn = Xbf + (((size_t)n * C_DIM) << 10);

    for (int kb = 0; kb < 256; kb += 32) {
        __syncthreads();
#pragma unroll
        for (int i = 0; i < 2; ++i) {
            int a = t + 256 * i;
            int row = a >> 2, c8 = a & 3;
            *(uint4*)(&Asm[row * 40 + 8 * c8]) =
                *(const uint4*)(&Mbf[(db + row) * C_DIM + kb + 8 * c8]);
        }
#pragma unroll
        for (int i = 0; i < 16; ++i) {
            int idx = t + 256 * i;
            int hw = idx & 127, crow = idx >> 7;
            Bsm[hw * 34 + crow] = Xn[(((size_t)(kb + crow)) << 10) + hwb + hw];
        }
        __syncthreads();

        short8 af[4], bfr[4];
#pragma unroll
        for (int mt = 0; mt < 4; ++mt)
            af[mt] = *(const short8*)(&Asm[(64 * wy + 16 * mt + l16) * 40 + 8 * quad]);
#pragma unroll
        for (int nt = 0; nt < 4; ++nt) {
            union { short8 s; unsigned u[4]; } tmp;
            const unsigned short* bp = &Bsm[(64 * wx + 16 * nt + l16) * 34 + 8 * quad];
            tmp.u[0] = *(const unsigned*)(bp + 0);
            tmp.u[1] = *(const unsigned*)(bp + 2);
            tmp.u[2] = *(const unsigned*)(bp + 4);
            tmp.u[3] = *(const unsigned*)(bp + 6);
            bfr[nt] = tmp.s;
        }
#pragma unroll
        for (int mt = 0; mt < 4; ++mt)
#pragma unroll
            for (int nt = 0; nt < 4; ++nt)
                acc[mt][nt] = __builtin_amdgcn_mfma_f32_16x16x32_bf16(af[mt], bfr[nt], acc[mt][nt], 0, 0, 0);
    }

#pragma unroll
    for (int mt = 0; mt < 4; ++mt)
#pragma unroll
        for (int r = 0; r < 4; ++r) {
            int d = db + 64 * wy + 16 * mt + quad * 4 + r;
            float off = moff[d];
#pragma unroll
            for (int nt = 0; nt < 4; ++nt) {
                int hw = hwb + 64 * wx + 16 * nt + l16;
                out[(((size_t)(n * C_DIM + d)) << 10) + hw] = acc[mt][nt][r] - off;
            }
        }
}

// ---------------------------------------------------------------------------
extern "C" void kernel_launch(void* const* d_in, const int* in_sizes, int n_in,
                              void* d_out, int out_size, void* d_ws, size_t ws_size,
                              hipStream_t stream) {
    const float* X = (const float*)d_in[0];        // (64,256,32,32)
    const float* R = (const float*)d_in[1];        // (1,256,256)
    float* out = (float*)d_out;
    float* ws  = (float*)d_ws;

    float* musum = ws;                         // 256
    float* scal  = ws + 256;                   // 16
    float* moff  = ws + 272;                   // 256
    float* G     = ws + 528;                   // 65536 (raw gram, 3 tiles)
    float* Sig   = G + 65536;                  // Sigma_N fp32
    float* P     = Sig + 65536;
    float* T1    = P + 65536;
    float* T2    = T1 + 65536;
    unsigned short* Mbf = (unsigned short*)(T2 + 65536);          // 65536 ushort
    unsigned short* Xbf = Mbf + 65536;                            // 16M ushort (32 MB)

    // zero musum/scal/moff/G in one memset
    hipMemsetAsync(ws, 0, (528 + 65536) * sizeof(float), stream);

    prepass_kernel<<<4096, 256, 0, stream>>>(X, Xbf, musum);
    gram_mfma<<<dim3(3, 128), 512, 0, stream>>>(Xbf, G);
    scal_kernel<<<1, 256, 0, stream>>>(G, musum, scal);
    init_kernel<<<64, 256, 0, stream>>>(G, musum, scal, Sig, P);

    for (int it = 1; it < 10; ++it) {
        nsA_kernel<<<dim3(16, 2), 256, 0, stream>>>(P, Sig, T1, T2);
        nsB_kernel<<<16, 256, 0, stream>>>(T1, T2, P);
    }

    rot_kernel<<<16, 256, 0, stream>>>(R, P, scal, musum, Mbf, moff);
    out_mfma<<<dim3(8, 2, 64), 256, 0, stream>>>(Xbf, Mbf, moff, out);
}

// Round 5
// 381.727 us; speedup vs baseline: 2.3539x; 1.8638x over previous
//
#include <hip/hip_runtime.h>
#include <math.h>

#define C_DIM 256
#define HW_DIM 1024
#define N_DIM 64
#define M_TOTAL (N_DIM * HW_DIM)   // 65536
#define EPS_F 1e-5f

typedef __attribute__((ext_vector_type(8))) short short8;   // 8 bf16 (MFMA A/B frag)
typedef __attribute__((ext_vector_type(4))) float v4f;      // MFMA C/D frag

// fp32 -> bf16 round-to-nearest-even
__device__ __forceinline__ unsigned short f2bf(float x) {
    unsigned u = __float_as_uint(x);
    u = (u + 0x7FFFu + ((u >> 16) & 1u)) >> 16;
    return (unsigned short)u;
}
__device__ __forceinline__ float bf2f(unsigned short h) {
    return __uint_as_float(((unsigned)h) << 16);
}
__device__ __forceinline__ unsigned pack2(float lo, float hi) {
    return (unsigned)f2bf(lo) | ((unsigned)f2bf(hi) << 16);
}
// split float4 into hi (bf16 RNE) and lo (bf16 of residual): ~fp32 precision in 2 bf16
__device__ __forceinline__ void split4(float4 v, uint2* hi, uint2* lo) {
    unsigned short h0 = f2bf(v.x), h1 = f2bf(v.y), h2 = f2bf(v.z), h3 = f2bf(v.w);
    float r0 = v.x - bf2f(h0), r1 = v.y - bf2f(h1), r2 = v.z - bf2f(h2), r3 = v.w - bf2f(h3);
    hi->x = (unsigned)h0 | ((unsigned)h1 << 16);
    hi->y = (unsigned)h2 | ((unsigned)h3 << 16);
    lo->x = (unsigned)f2bf(r0) | ((unsigned)f2bf(r1) << 16);
    lo->y = (unsigned)f2bf(r2) | ((unsigned)f2bf(r3) << 16);
}

// ---------------------------------------------------------------------------
// Kernel 1: Xbf = bf16(X) + per-channel sums (atomic). grid 4096, block 256.
__global__ void prepass_kernel(const float* __restrict__ X, unsigned short* __restrict__ Xbf,
                               float* __restrict__ musum) {
    int b = blockIdx.x;
    int t = threadIdx.x;
    int r = t >> 6;
    int l = t & 63;
    size_t row = (size_t)(4 * b + r);
    const float4* src = (const float4*)(X + (row << 10));
    uint2* dst = (uint2*)(Xbf + (row << 10));
    float s = 0.f;
#pragma unroll
    for (int j = 0; j < 4; ++j) {
        float4 v = src[l + 64 * j];
        uint2 p; p.x = pack2(v.x, v.y); p.y = pack2(v.z, v.w);
        dst[l + 64 * j] = p;
        s += v.x + v.y + v.z + v.w;
    }
    for (int off = 32; off > 0; off >>= 1) s += __shfl_down(s, off);
    if (l == 0) atomicAdd(&musum[(4 * b + r) & 255], s);
}

// ---------------------------------------------------------------------------
// Kernel 2: raw Gram G += X X^T via bf16 MFMA, symmetric (3 unique tiles).
// grid (3 tiles, 128 k-splits), block 512 (8 waves: 2x4 of 64x32).
__global__ __launch_bounds__(512, 3)
void gram_mfma(const unsigned short* __restrict__ Xbf, float* __restrict__ G) {
    int tile = blockIdx.x;               // 0:(0,0) 1:(0,128) 2:(128,128)
    int ci = (tile >> 1) * 128;
    int cj = (tile == 0) ? 0 : 128;
    int ks = blockIdx.y;                 // 0..127, K=512 each
    int t = threadIdx.x, wave = t >> 6, lane = t & 63;
    int wy = wave >> 2, wx = wave & 3;
    int quad = lane >> 4, l16 = lane & 15;

    __shared__ __align__(16) unsigned short As[128 * 72];
    __shared__ __align__(16) unsigned short Bs[128 * 72];
    const unsigned short* Bsrc = (ci == cj) ? As : Bs;

    v4f acc[4][2] = {};
    int n = ks >> 1;
    int hwbase = (ks & 1) * 512;
    const unsigned short* base = Xbf + (((size_t)n * C_DIM) << 10);
    int srow = t >> 2;
    int schunk = t & 3;

    for (int s = 0; s < 8; ++s) {
        int k0 = hwbase + s * 64;
        __syncthreads();
#pragma unroll
        for (int h = 0; h < 2; ++h) {
            int ch = schunk + 4 * h;
            *(uint4*)&As[srow * 72 + ch * 8] =
                *(const uint4*)&base[(((size_t)(ci + srow)) << 10) + k0 + ch * 8];
            if (ci != cj)
                *(uint4*)&Bs[srow * 72 + ch * 8] =
                    *(const uint4*)&base[(((size_t)(cj + srow)) << 10) + k0 + ch * 8];
        }
        __syncthreads();

        short8 af[4][2], bfr[2][2];
#pragma unroll
        for (int mt = 0; mt < 4; ++mt)
#pragma unroll
            for (int kh = 0; kh < 2; ++kh)
                af[mt][kh] = *(const short8*)&As[(64 * wy + 16 * mt + l16) * 72 + kh * 32 + quad * 8];
#pragma unroll
        for (int nt = 0; nt < 2; ++nt)
#pragma unroll
            for (int kh = 0; kh < 2; ++kh)
                bfr[nt][kh] = *(const short8*)&Bsrc[(32 * wx + 16 * nt + l16) * 72 + kh * 32 + quad * 8];
#pragma unroll
        for (int kh = 0; kh < 2; ++kh)
#pragma unroll
            for (int mt = 0; mt < 4; ++mt)
#pragma unroll
                for (int nt = 0; nt < 2; ++nt)
                    acc[mt][nt] = __builtin_amdgcn_mfma_f32_16x16x32_bf16(af[mt][kh], bfr[nt][kh], acc[mt][nt], 0, 0, 0);
    }

#pragma unroll
    for (int mt = 0; mt < 4; ++mt)
#pragma unroll
        for (int nt = 0; nt < 2; ++nt)
#pragma unroll
            for (int r = 0; r < 4; ++r) {
                int row = ci + 64 * wy + 16 * mt + 4 * quad + r;
                int col = cj + 32 * wx + 16 * nt + l16;
                atomicAdd(&G[row * C_DIM + col], acc[mt][nt][r]);
            }
}

// ---------------------------------------------------------------------------
// Kernel 3: scal[0]=1/trace(Sigma), scal[1]=sqrt(scal[0]). grid 1, block 256.
__global__ void scal_kernel(const float* __restrict__ G, const float* __restrict__ musum,
                            float* __restrict__ scal) {
    int t = threadIdx.x;
    float mu = musum[t] * (1.0f / M_TOTAL);
    float d = G[t * (C_DIM + 1)] * (1.0f / M_TOTAL) - mu * mu + EPS_F;
    __shared__ float red[256];
    red[t] = d;
    __syncthreads();
    for (int off = 128; off > 0; off >>= 1) {
        if (t < off) red[t] += red[t + off];
        __syncthreads();
    }
    if (t == 0) {
        float tr_rec = 1.0f / red[0];
        scal[0] = tr_rec;
        scal[1] = sqrtf(tr_rec);
    }
}

// ---------------------------------------------------------------------------
// Kernel 4: Sig = Sigma_N (fp32, mirrored -> symmetric), P = 1.5I - 0.5*Sig.
__global__ void init_kernel(const float* __restrict__ G, const float* __restrict__ musum,
                            const float* __restrict__ scal, float* __restrict__ Sig,
                            float* __restrict__ P) {
    float trr = scal[0];
    int base = blockIdx.x * 1024 + threadIdx.x;
#pragma unroll
    for (int j = 0; j < 4; ++j) {
        int idx = base + j * 256;
        int r = idx >> 8, c = idx & 255;
        float g = (r >= 128 && c < 128) ? G[c * C_DIM + r] : G[idx];
        float mu_r = musum[r] * (1.0f / M_TOTAL);
        float mu_c = musum[c] * (1.0f / M_TOTAL);
        float sig = (g * (1.0f / M_TOTAL) - mu_r * mu_c + ((r == c) ? EPS_F : 0.f)) * trr;
        Sig[idx] = sig;
        P[idx] = ((r == c) ? 1.5f : 0.f) - 0.5f * sig;
    }
}

// ---------------------------------------------------------------------------
// MFMA 64x64-tile matmul core, K=256, bf16 hi/lo split (~fp32 precision).
// REQUIRES: B symmetric (stages B rows as columns). block 256 (4 waves 2x2).
// Fills acc[2][2] (wave covers 32x32; mt,nt over 16x16 MFMA tiles).
__device__ __forceinline__ void mm_mfma64(const float* __restrict__ A, const float* __restrict__ B,
                                          int ci, int cj, v4f acc[2][2],
                                          unsigned short* Ah, unsigned short* Al,
                                          unsigned short* Bh, unsigned short* Bl) {
    int t = threadIdx.x, wave = t >> 6, lane = t & 63;
    int wy = wave >> 1, wx = wave & 1;
    int quad = lane >> 4, l16 = lane & 15;
    int row = t >> 2, cg = (t & 3) * 16;

    for (int kb = 0; kb < 256; kb += 64) {
        __syncthreads();
#pragma unroll
        for (int i = 0; i < 4; ++i) {
            float4 va = *(const float4*)&A[(ci + row) * C_DIM + kb + cg + 4 * i];
            uint2 hi, lo;
            split4(va, &hi, &lo);
            *(uint2*)&Ah[row * 72 + cg + 4 * i] = hi;
            *(uint2*)&Al[row * 72 + cg + 4 * i] = lo;
            float4 vb = *(const float4*)&B[(cj + row) * C_DIM + kb + cg + 4 * i];
            split4(vb, &hi, &lo);
            *(uint2*)&Bh[row * 72 + cg + 4 * i] = hi;
            *(uint2*)&Bl[row * 72 + cg + 4 * i] = lo;
        }
        __syncthreads();

        short8 fah[2][2], fal[2][2], fbh[2][2], fbl[2][2];
#pragma unroll
        for (int mt = 0; mt < 2; ++mt)
#pragma unroll
            for (int kh = 0; kh < 2; ++kh) {
                int off = (32 * wy + 16 * mt + l16) * 72 + kh * 32 + quad * 8;
                fah[mt][kh] = *(const short8*)&Ah[off];
                fal[mt][kh] = *(const short8*)&Al[off];
            }
#pragma unroll
        for (int nt = 0; nt < 2; ++nt)
#pragma unroll
            for (int kh = 0; kh < 2; ++kh) {
                int off = (32 * wx + 16 * nt + l16) * 72 + kh * 32 + quad * 8;
                fbh[nt][kh] = *(const short8*)&Bh[off];
                fbl[nt][kh] = *(const short8*)&Bl[off];
            }
#pragma unroll
        for (int kh = 0; kh < 2; ++kh)
#pragma unroll
            for (int mt = 0; mt < 2; ++mt)
#pragma unroll
                for (int nt = 0; nt < 2; ++nt) {
                    acc[mt][nt] = __builtin_amdgcn_mfma_f32_16x16x32_bf16(fah[mt][kh], fbh[nt][kh], acc[mt][nt], 0, 0, 0);
                    acc[mt][nt] = __builtin_amdgcn_mfma_f32_16x16x32_bf16(fah[mt][kh], fbl[nt][kh], acc[mt][nt], 0, 0, 0);
                    acc[mt][nt] = __builtin_amdgcn_mfma_f32_16x16x32_bf16(fal[mt][kh], fbh[nt][kh], acc[mt][nt], 0, 0, 0);
                }
    }
}

#define NS_SHARED \
    __shared__ __align__(16) unsigned short Ah[64 * 72]; \
    __shared__ __align__(16) unsigned short Al[64 * 72]; \
    __shared__ __align__(16) unsigned short Bh[64 * 72]; \
    __shared__ __align__(16) unsigned short Bl[64 * 72];

// NS level 1: T1 = P@P (y=0), T2 = P@Sig (y=1). grid (16,2), block 256.
__global__ void nsA_kernel(const float* __restrict__ P, const float* __restrict__ Sig,
                           float* __restrict__ T1, float* __restrict__ T2) {
    NS_SHARED
    int ci = (blockIdx.x >> 2) * 64, cj = (blockIdx.x & 3) * 64;
    const float* B = (blockIdx.y == 0) ? P : Sig;
    float* D = (blockIdx.y == 0) ? T1 : T2;
    v4f acc[2][2] = {};
    mm_mfma64(P, B, ci, cj, acc, Ah, Al, Bh, Bl);

    int wave = threadIdx.x >> 6, lane = threadIdx.x & 63;
    int wy = wave >> 1, wx = wave & 1, quad = lane >> 4, l16 = lane & 15;
#pragma unroll
    for (int mt = 0; mt < 2; ++mt)
#pragma unroll
        for (int nt = 0; nt < 2; ++nt)
#pragma unroll
            for (int r = 0; r < 4; ++r) {
                int rr = ci + 32 * wy + 16 * mt + 4 * quad + r;
                int cc = cj + 32 * wx + 16 * nt + l16;
                D[rr * C_DIM + cc] = acc[mt][nt][r];
            }
}

// NS level 2: P = 1.5P - 0.5*(T1@T2). grid 16, block 256. (T2 symmetric: P,Sig commute)
__global__ void nsB_kernel(const float* __restrict__ T1, const float* __restrict__ T2,
                           float* __restrict__ P) {
    NS_SHARED
    int ci = (blockIdx.x >> 2) * 64, cj = (blockIdx.x & 3) * 64;
    v4f acc[2][2] = {};
    mm_mfma64(T1, T2, ci, cj, acc, Ah, Al, Bh, Bl);

    int wave = threadIdx.x >> 6, lane = threadIdx.x & 63;
    int wy = wave >> 1, wx = wave & 1, quad = lane >> 4, l16 = lane & 15;
#pragma unroll
    for (int mt = 0; mt < 2; ++mt)
#pragma unroll
        for (int nt = 0; nt < 2; ++nt)
#pragma unroll
            for (int r = 0; r < 4; ++r) {
                int rr = ci + 32 * wy + 16 * mt + 4 * quad + r;
                int cc = cj + 32 * wx + 16 * nt + l16;
                int idx = rr * C_DIM + cc;
                P[idx] = 1.5f * P[idx] - 0.5f * acc[mt][nt][r];
            }
}

// rot: M = (R@P)*scal[1] -> Mbf (bf16) + moff[d] = dot(M[d,:], mu). grid 16, block 256.
__global__ void rot_kernel(const float* __restrict__ R, const float* __restrict__ P,
                           const float* __restrict__ scal, const float* __restrict__ musum,
                           unsigned short* __restrict__ Mbf, float* __restrict__ moff) {
    NS_SHARED
    int ci = (blockIdx.x >> 2) * 64, cj = (blockIdx.x & 3) * 64;
    v4f acc[2][2] = {};
    mm_mfma64(R, P, ci, cj, acc, Ah, Al, Bh, Bl);

    int wave = threadIdx.x >> 6, lane = threadIdx.x & 63;
    int wy = wave >> 1, wx = wave & 1, quad = lane >> 4, l16 = lane & 15;
    float s1 = scal[1];
    float muc[2];
#pragma unroll
    for (int nt = 0; nt < 2; ++nt)
        muc[nt] = musum[cj + 32 * wx + 16 * nt + l16] * (1.0f / M_TOTAL);
#pragma unroll
    for (int mt = 0; mt < 2; ++mt)
#pragma unroll
        for (int r = 0; r < 4; ++r) {
            int rr = ci + 32 * wy + 16 * mt + 4 * quad + r;
            float s = 0.f;
#pragma unroll
            for (int nt = 0; nt < 2; ++nt) {
                float val = acc[mt][nt][r] * s1;
                Mbf[rr * C_DIM + cj + 32 * wx + 16 * nt + l16] = f2bf(val);
                s += val * muc[nt];
            }
            s += __shfl_xor(s, 1); s += __shfl_xor(s, 2);
            s += __shfl_xor(s, 4); s += __shfl_xor(s, 8);
            if (l16 == 0) atomicAdd(&moff[rr], s);
        }
}

// ---------------------------------------------------------------------------
// Kernel 6: out[n,d,hw] = sum_c Mbf[d,c]*Xbf[n,c,hw] - moff[d]  via MFMA.
// grid: (8 hw-tiles, 2 d-tiles, 64 n), block 256 (4 waves of 64x64).
// Epilogue: LDS transpose -> float4 coalesced stores (full 128B lines).
__global__ void out_mfma(const unsigned short* __restrict__ Xbf,
                         const unsigned short* __restrict__ Mbf,
                         const float* __restrict__ moff, float* __restrict__ out) {
    int hwb = blockIdx.x * 128;
    int db  = blockIdx.y * 128;
    int n   = blockIdx.z;
    int t = threadIdx.x, wave = t >> 6, lane = t & 63;
    int wy = wave >> 1, wx = wave & 1, quad = lane >> 4, l16 = lane & 15;

    __shared__ __align__(16) unsigned short Asm[128 * 40];
    __shared__ __align__(16) unsigned short Bsm[128 * 34];
    __shared__ __align__(16) float Ep[4 * 16 * 68];   // per-wave 16x64 epilogue buffer

    v4f acc[4][4] = {};
    const unsigned short* Xn = Xbf + (((size_t)n * C_DIM) << 10);

    for (int kb = 0; kb < 256; kb += 32) {
        __syncthreads();
#pragma unroll
        for (int i = 0; i < 2; ++i) {
            int a = t + 256 * i;
            int row = a >> 2, c8 = a & 3;
            *(uint4*)(&Asm[row * 40 + 8 * c8]) =
                *(const uint4*)(&Mbf[(db + row) * C_DIM + kb + 8 * c8]);
        }
#pragma unroll
        for (int i = 0; i < 16; ++i) {
            int idx = t + 256 * i;
            int hw = idx & 127, crow = idx >> 7;
            Bsm[hw * 34 + crow] = Xn[(((size_t)(kb + crow)) << 10) + hwb + hw];
        }
        __syncthreads();

        short8 af[4], bfr[4];
#pragma unroll
        for (int mt = 0; mt < 4; ++mt)
            af[mt] = *(const short8*)(&Asm[(64 * wy + 16 * mt + l16) * 40 + 8 * quad]);
#pragma unroll
        for (int nt = 0; nt < 4; ++nt) {
            union { short8 s; unsigned u[4]; } tmp;
            const unsigned short* bp = &Bsm[(64 * wx + 16 * nt + l16) * 34 + 8 * quad];
            tmp.u[0] = *(const unsigned*)(bp + 0);
            tmp.u[1] = *(const unsigned*)(bp + 2);
            tmp.u[2] = *(const unsigned*)(bp + 4);
            tmp.u[3] = *(const unsigned*)(bp + 6);
            bfr[nt] = tmp.s;
        }
#pragma unroll
        for (int mt = 0; mt < 4; ++mt)
#pragma unroll
            for (int nt = 0; nt < 4; ++nt)
                acc[mt][nt] = __builtin_amdgcn_mfma_f32_16x16x32_bf16(af[mt], bfr[nt], acc[mt][nt], 0, 0, 0);
    }

    float* W = &Ep[wave * 16 * 68];
#pragma unroll
    for (int mt = 0; mt < 4; ++mt) {
        // dump this wave's 16x64 tile (row = 4*quad+r, col = 16*nt+l16), moff folded in
#pragma unroll
        for (int r = 0; r < 4; ++r) {
            float off = moff[db + 64 * wy + 16 * mt + 4 * quad + r];
#pragma unroll
            for (int nt = 0; nt < 4; ++nt)
                W[(4 * quad + r) * 68 + 16 * nt + l16] = acc[mt][nt][r] - off;
        }
        __syncthreads();   // orders wave-local LDS ops; uniform across block
        // read back transposed-in-lane: 16 lanes x float4 = 256B contiguous per row
#pragma unroll
        for (int j = 0; j < 4; ++j) {
            int row = 4 * j + quad;
            float4 v = *(const float4*)&W[row * 68 + 4 * l16];
            int d = db + 64 * wy + 16 * mt + row;
            int hw = hwb + 64 * wx + 4 * l16;
            *(float4*)&out[(((size_t)(n * C_DIM + d)) << 10) + hw] = v;
        }
        __syncthreads();
    }
}

// ---------------------------------------------------------------------------
extern "C" void kernel_launch(void* const* d_in, const int* in_sizes, int n_in,
                              void* d_out, int out_size, void* d_ws, size_t ws_size,
                              hipStream_t stream) {
    const float* X = (const float*)d_in[0];        // (64,256,32,32)
    const float* R = (const float*)d_in[1];        // (1,256,256)
    float* out = (float*)d_out;
    float* ws  = (float*)d_ws;

    float* musum = ws;                         // 256
    float* scal  = ws + 256;                   // 16
    float* moff  = ws + 272;                   // 256
    float* G     = ws + 528;                   // 65536 (raw gram, 3 tiles)
    float* Sig   = G + 65536;                  // Sigma_N fp32 (symmetric)
    float* P     = Sig + 65536;
    float* T1    = P + 65536;
    float* T2    = T1 + 65536;
    unsigned short* Mbf = (unsigned short*)(T2 + 65536);   // 65536 ushort
    unsigned short* Xbf = Mbf + 65536;                     // 16M ushort (32 MB)

    hipMemsetAsync(ws, 0, (528 + 65536) * sizeof(float), stream);

    prepass_kernel<<<4096, 256, 0, stream>>>(X, Xbf, musum);
    gram_mfma<<<dim3(3, 128), 512, 0, stream>>>(Xbf, G);
    scal_kernel<<<1, 256, 0, stream>>>(G, musum, scal);
    init_kernel<<<64, 256, 0, stream>>>(G, musum, scal, Sig, P);

    for (int it = 1; it < 10; ++it) {
        nsA_kernel<<<dim3(16, 2), 256, 0, stream>>>(P, Sig, T1, T2);
        nsB_kernel<<<16, 256, 0, stream>>>(T1, T2, P);
    }

    rot_kernel<<<16, 256, 0, stream>>>(R, P, scal, musum, Mbf, moff);
    out_mfma<<<dim3(8, 2, 64), 256, 0, stream>>>(Xbf, Mbf, moff, out);
}